// Round 4
// baseline (253.262 us; speedup 1.0000x reference)
//
#include <hip/hip_runtime.h>
#include <stdint.h>

#define UNITS 4096
#define NB0   2048   // 11-bit digit bins

// LDS-only barrier: drain this wave's LDS ops then s_barrier, WITHOUT
// draining vmcnt (keeps global loads in flight across barriers).
__device__ __forceinline__ void lds_barrier() {
    asm volatile("s_waitcnt lgkmcnt(0)" ::: "memory");
    __builtin_amdgcn_s_barrier();
}

// order-preserving float->uint map (ascending)
__device__ __forceinline__ uint32_t flipu(uint32_t b) {
    return b ^ (uint32_t)(((int32_t)b >> 31) | (int32_t)0x80000000);
}

// unflip: recover float from ordered uint
__device__ __forceinline__ float unflip(uint32_t u) {
    uint32_t m = ~(uint32_t)((int32_t)u >> 31) | 0x80000000u;
    return __uint_as_float(u ^ m);
}

// One block = 2 rows, selected concurrently with twin histograms.
// Exact 3-pass MSB-first radix select (11/11/10 bits) per row.
__global__ __launch_bounds__(256, 8) void ksparse_select_kernel(
        const float* __restrict__ X, float* __restrict__ out, int kidx, int nrows) {
    __shared__ uint32_t histA[NB0];  // 8 KiB
    __shared__ uint32_t histB[NB0];  // 8 KiB
    __shared__ uint32_t wsum[8];     // inclA x4, inclB x4
    __shared__ uint32_t sel[4];      // {binA, remA, binB, remB}

    const int t    = threadIdx.x;
    const int w    = t >> 6;
    const int lane = t & 63;

    uint4* hA4 = reinterpret_cast<uint4*>(histA);
    uint4* hB4 = reinterpret_cast<uint4*>(histB);
    const uint4 z4 = make_uint4(0u, 0u, 0u, 0u);
    hA4[2 * t] = z4; hA4[2 * t + 1] = z4;   // thread t owns bins [8t,8t+8)
    hB4[2 * t] = z4; hB4[2 * t + 1] = z4;

    const int rowA = (int)blockIdx.x * 2;
    const int rowB_real = rowA + 1;
    const int rowB = (rowB_real < nrows) ? rowB_real : rowA;  // safe replay if odd

    // load both rows, convert to ordered uints
    uint32_t uuA[16], uuB[16];
    {
        const float4* Xa = reinterpret_cast<const float4*>(X + (size_t)rowA * UNITS);
        const float4* Xb = reinterpret_cast<const float4*>(X + (size_t)rowB * UNITS);
        float4 va[4], vb[4];
#pragma unroll
        for (int j = 0; j < 4; ++j) va[j] = Xa[j * 256 + t];
#pragma unroll
        for (int j = 0; j < 4; ++j) vb[j] = Xb[j * 256 + t];
#pragma unroll
        for (int j = 0; j < 4; ++j) {
            uuA[4 * j + 0] = flipu(__float_as_uint(va[j].x));
            uuA[4 * j + 1] = flipu(__float_as_uint(va[j].y));
            uuA[4 * j + 2] = flipu(__float_as_uint(va[j].z));
            uuA[4 * j + 3] = flipu(__float_as_uint(va[j].w));
            uuB[4 * j + 0] = flipu(__float_as_uint(vb[j].x));
            uuB[4 * j + 1] = flipu(__float_as_uint(vb[j].y));
            uuB[4 * j + 2] = flipu(__float_as_uint(vb[j].z));
            uuB[4 * j + 3] = flipu(__float_as_uint(vb[j].w));
        }
    }

    lds_barrier();  // hist zeroed everywhere

    // pass-0 histograms: top 11 bits, both rows (queues interleave in LDS pipe)
#pragma unroll
    for (int e = 0; e < 16; ++e) {
        atomicAdd(&histA[uuA[e] >> 21], 1u);
        atomicAdd(&histB[uuB[e] >> 21], 1u);
    }

    uint32_t kkA = (uint32_t)kidx, kkB = (uint32_t)kidx;
    uint32_t prA = 0, prB = 0;

#pragma unroll
    for (int pass = 0; pass < 3; ++pass) {
        lds_barrier();  // histogram atomics visible

        // read my 8 bins of each hist, immediately re-zero
        uint4 a0 = hA4[2 * t], a1 = hA4[2 * t + 1];
        uint4 b0 = hB4[2 * t], b1 = hB4[2 * t + 1];
        hA4[2 * t] = z4; hA4[2 * t + 1] = z4;
        hB4[2 * t] = z4; hB4[2 * t + 1] = z4;
        uint32_t hA[8] = {a0.x, a0.y, a0.z, a0.w, a1.x, a1.y, a1.z, a1.w};
        uint32_t hB[8] = {b0.x, b0.y, b0.z, b0.w, b1.x, b1.y, b1.z, b1.w};
        uint32_t sA = 0, sB = 0;
#pragma unroll
        for (int i = 0; i < 8; ++i) { sA += hA[i]; sB += hB[i]; }

        // dual wave inclusive scan (independent chains dual-issue)
        uint32_t iA = sA, iB = sB;
#pragma unroll
        for (int d = 1; d < 64; d <<= 1) {
            uint32_t xA = __shfl_up(iA, d);
            uint32_t xB = __shfl_up(iB, d);
            if (lane >= d) { iA += xA; iB += xB; }
        }
        if (lane == 63) { wsum[w] = iA; wsum[4 + w] = iB; }
        lds_barrier();  // wsum ready (also covers re-zero visibility)

        uint32_t offA = 0, offB = 0;
#pragma unroll
        for (int ww = 0; ww < 4; ++ww) {
            offA += (ww < w) ? wsum[ww] : 0u;
            offB += (ww < w) ? wsum[4 + ww] : 0u;
        }
        iA += offA; iB += offB;
        const uint32_t exA = iA - sA, exB = iB - sB;

        if (kkA >= exA && kkA < exA + sA) {
            uint32_t c = exA, bin = 0, rem = 0;
#pragma unroll
            for (int i = 0; i < 8; ++i) {
                if (kkA < c + hA[i]) { bin = 8u * t + i; rem = kkA - c; break; }
                c += hA[i];
            }
            sel[0] = bin; sel[1] = rem;
        }
        if (kkB >= exB && kkB < exB + sB) {
            uint32_t c = exB, bin = 0, rem = 0;
#pragma unroll
            for (int i = 0; i < 8; ++i) {
                if (kkB < c + hB[i]) { bin = 8u * t + i; rem = kkB - c; break; }
                c += hB[i];
            }
            sel[2] = bin; sel[3] = rem;
        }
        lds_barrier();  // sel ready

        const uint32_t binA = sel[0], binB = sel[2];
        kkA = sel[1]; kkB = sel[3];

        if (pass == 0) {
            prA = binA; prB = binB;  // bits [31:21]
#pragma unroll
            for (int e = 0; e < 16; ++e) {
                if ((uuA[e] >> 21) == prA) atomicAdd(&histA[(uuA[e] >> 10) & 2047u], 1u);
                if ((uuB[e] >> 21) == prB) atomicAdd(&histB[(uuB[e] >> 10) & 2047u], 1u);
            }
        } else if (pass == 1) {
            prA = (prA << 11) | binA;  // bits [31:10]
            prB = (prB << 11) | binB;
#pragma unroll
            for (int e = 0; e < 16; ++e) {
                if ((uuA[e] >> 10) == prA) atomicAdd(&histA[uuA[e] & 1023u], 1u);
                if ((uuB[e] >> 10) == prB) atomicAdd(&histB[uuB[e] & 1023u], 1u);
            }
        } else {
            prA = (prA << 10) | binA;  // full 32-bit pattern of theta
            prB = (prB << 10) | binB;
        }
    }

    // masked write-back from registers (ordered-uint compare is exact)
    {
        float4* Oa = reinterpret_cast<float4*>(out + (size_t)rowA * UNITS);
#pragma unroll
        for (int j = 0; j < 4; ++j) {
            float4 o;
            uint32_t u;
            u = uuA[4 * j + 0]; o.x = (u >= prA) ? unflip(u) : 0.0f;
            u = uuA[4 * j + 1]; o.y = (u >= prA) ? unflip(u) : 0.0f;
            u = uuA[4 * j + 2]; o.z = (u >= prA) ? unflip(u) : 0.0f;
            u = uuA[4 * j + 3]; o.w = (u >= prA) ? unflip(u) : 0.0f;
            Oa[j * 256 + t] = o;
        }
    }
    if (rowB_real < nrows) {
        float4* Ob = reinterpret_cast<float4*>(out + (size_t)rowB * UNITS);
#pragma unroll
        for (int j = 0; j < 4; ++j) {
            float4 o;
            uint32_t u;
            u = uuB[4 * j + 0]; o.x = (u >= prB) ? unflip(u) : 0.0f;
            u = uuB[4 * j + 1]; o.y = (u >= prB) ? unflip(u) : 0.0f;
            u = uuB[4 * j + 2]; o.z = (u >= prB) ? unflip(u) : 0.0f;
            u = uuB[4 * j + 3]; o.w = (u >= prB) ? unflip(u) : 0.0f;
            Ob[j * 256 + t] = o;
        }
    }
}

extern "C" void kernel_launch(void* const* d_in, const int* in_sizes, int n_in,
                              void* d_out, int out_size, void* d_ws, size_t ws_size,
                              hipStream_t stream) {
    const float* X = (const float*)d_in[0];
    float* out = (float*)d_out;
    const int rows = in_sizes[0] / UNITS;
    const int kidx = (int)(0.7 * UNITS);  // 2867
    const int grid = (rows + 1) / 2;
    ksparse_select_kernel<<<grid, 256, 0, stream>>>(X, out, kidx, rows);
}

// Round 5
// 126.387 us; speedup vs baseline: 2.0039x; 2.0039x over previous
//
#include <hip/hip_runtime.h>
#include <stdint.h>

#define UNITS 4096
#define RPB   8     // rows per block when rows % 8 == 0 (16384 -> 2048 blocks)

// LDS-only barrier: drain this wave's LDS ops then s_barrier, WITHOUT
// draining vmcnt (keeps DMA prefetch + output stores in flight).
__device__ __forceinline__ void lds_barrier() {
    asm volatile("s_waitcnt lgkmcnt(0)" ::: "memory");
    __builtin_amdgcn_s_barrier();
}

// order-preserving float->uint map (ascending) and inverse
__device__ __forceinline__ uint32_t flipu(uint32_t b) {
    return b ^ (uint32_t)(((int32_t)b >> 31) | (int32_t)0x80000000);
}
__device__ __forceinline__ float unflip(uint32_t u) {
    uint32_t m = ~(uint32_t)((int32_t)u >> 31) | 0x80000000u;
    return __uint_as_float(u ^ m);
}

// async global->LDS, 16B per lane; lds dst is wave-uniform base, HW adds lane*16
__device__ __forceinline__ void dma16(const float* g, float* l) {
    __builtin_amdgcn_global_load_lds(
        (const __attribute__((address_space(1))) void*)g,
        (__attribute__((address_space(3))) void*)l, 16, 0, 0);
}

// One block, 256 threads; rpb rows at row = r*nblocks + blockIdx (banded).
// Exact 3-pass MSB-first radix select (11/11/10 bits), hist packed u16x2.
__global__ __launch_bounds__(256, 6) void ksparse_select_kernel(
        const float* __restrict__ X, float* __restrict__ out,
        int kidx, int nblocks, int rpb) {
    __shared__ float    buf[UNITS];   // 16 KiB DMA target (next row)
    __shared__ uint32_t hist[1024];   // 2048 bins packed as u16 pairs (4 KiB)
    __shared__ uint32_t wsum[4];
    __shared__ uint32_t sel[2];

    const int t    = threadIdx.x;
    const int w    = t >> 6;
    const int lane = t & 63;

    uint4* h4 = reinterpret_cast<uint4*>(hist);
    const uint4 z4 = make_uint4(0u, 0u, 0u, 0u);
    h4[t] = z4;   // thread t owns packed words [4t,4t+4) = logical bins [8t,8t+8)

    // row 0 straight to registers
    uint32_t uu[16];
    {
        const float4* Xv = reinterpret_cast<const float4*>(X + (size_t)blockIdx.x * UNITS);
        float4 v[4];
#pragma unroll
        for (int j = 0; j < 4; ++j) v[j] = Xv[j * 256 + t];
#pragma unroll
        for (int j = 0; j < 4; ++j) {
            uu[4 * j + 0] = flipu(__float_as_uint(v[j].x));
            uu[4 * j + 1] = flipu(__float_as_uint(v[j].y));
            uu[4 * j + 2] = flipu(__float_as_uint(v[j].z));
            uu[4 * j + 3] = flipu(__float_as_uint(v[j].w));
        }
    }
    // prefetch row 1 into LDS (no destination registers -> nothing to spill/sink)
    if (rpb > 1) {
        const float* g = X + ((size_t)nblocks + blockIdx.x) * UNITS;
        const int base = (w << 6);   // wave-uniform
#pragma unroll
        for (int j = 0; j < 4; ++j)
            dma16(g + 4 * (j * 256 + t), buf + 4 * (j * 256 + base));
    }

    lds_barrier();  // hist zeroed everywhere

#pragma unroll 1
    for (int r = 0;; ++r) {
        // ---- pass-0 histogram: top 11 bits
#pragma unroll
        for (int e = 0; e < 16; ++e) {
            uint32_t b = uu[e] >> 21;
            atomicAdd(&hist[b >> 1], 1u << ((b & 1u) << 4));
        }

        uint32_t kk = (uint32_t)kidx, pref = 0;

#pragma unroll
        for (int pass = 0; pass < 3; ++pass) {
            lds_barrier();  // histogram atomics visible

            uint4 a = h4[t];
            h4[t] = z4;     // re-zero own words (only owner touches)
            uint32_t h[8] = {a.x & 0xffffu, a.x >> 16, a.y & 0xffffu, a.y >> 16,
                             a.z & 0xffffu, a.z >> 16, a.w & 0xffffu, a.w >> 16};
            uint32_t s = 0;
#pragma unroll
            for (int i = 0; i < 8; ++i) s += h[i];

            uint32_t incl = s;
#pragma unroll
            for (int d = 1; d < 64; d <<= 1) {
                uint32_t x = __shfl_up(incl, d);
                if (lane >= d) incl += x;
            }
            if (lane == 63) wsum[w] = incl;
            lds_barrier();  // wsum ready (+ re-zero visibility)

            uint32_t off = 0;
#pragma unroll
            for (int ww = 0; ww < 4; ++ww) off += (ww < w) ? wsum[ww] : 0u;
            incl += off;
            const uint32_t excl = incl - s;

            if (kk >= excl && kk < excl + s) {   // exactly one thread
                uint32_t c = excl, bin = 0, rem = 0;
#pragma unroll
                for (int i = 0; i < 8; ++i) {
                    if (kk < c + h[i]) { bin = 8u * t + i; rem = kk - c; break; }
                    c += h[i];
                }
                sel[0] = bin; sel[1] = rem;
            }
            lds_barrier();  // sel ready

            const uint32_t bin = sel[0];
            kk = sel[1];

            if (pass == 0) {
                pref = bin;  // bits [31:21]
#pragma unroll
                for (int e = 0; e < 16; ++e) {
                    if ((uu[e] >> 21) == pref) {
                        uint32_t b = (uu[e] >> 10) & 2047u;
                        atomicAdd(&hist[b >> 1], 1u << ((b & 1u) << 4));
                    }
                }
            } else if (pass == 1) {
                pref = (pref << 11) | bin;  // bits [31:10]
#pragma unroll
                for (int e = 0; e < 16; ++e) {
                    if ((uu[e] >> 10) == pref) {
                        uint32_t b = uu[e] & 1023u;
                        atomicAdd(&hist[b >> 1], 1u << ((b & 1u) << 4));
                    }
                }
            } else {
                pref = (pref << 10) | bin;  // full 32-bit pattern of theta
            }
        }
        const uint32_t tu = pref;

        // ---- masked write-back of row r (4 stores; the 4 newest VMEM ops)
        {
            float4* Ov = reinterpret_cast<float4*>(out + ((size_t)r * nblocks + blockIdx.x) * UNITS);
#pragma unroll
            for (int j = 0; j < 4; ++j) {
                float4 o;
                uint32_t u;
                u = uu[4 * j + 0]; o.x = (u >= tu) ? unflip(u) : 0.0f;
                u = uu[4 * j + 1]; o.y = (u >= tu) ? unflip(u) : 0.0f;
                u = uu[4 * j + 2]; o.z = (u >= tu) ? unflip(u) : 0.0f;
                u = uu[4 * j + 3]; o.w = (u >= tu) ? unflip(u) : 0.0f;
                Ov[j * 256 + t] = o;
            }
        }

        if (r + 1 >= rpb) break;

        // ---- consume prefetched row r+1 from LDS.
        // vmcnt retires in order; the 4 newest outstanding ops are our stores,
        // so <=4 outstanding  =>  every older DMA has landed.
        asm volatile("s_waitcnt vmcnt(4)" ::: "memory");
        __builtin_amdgcn_sched_barrier(0);
        {
            const float4* bv = reinterpret_cast<const float4*>(buf);
            float4 v[4];
#pragma unroll
            for (int j = 0; j < 4; ++j) v[j] = bv[j * 256 + t];  // own lane's bytes
            asm volatile("s_waitcnt lgkmcnt(0)" ::: "memory");   // v landed; buf reusable
            __builtin_amdgcn_sched_barrier(0);

            if (r + 2 < rpb) {   // prefetch row r+2 over the freed buffer
                const float* g = X + ((size_t)(r + 2) * nblocks + blockIdx.x) * UNITS;
                const int base = (w << 6);
#pragma unroll
                for (int j = 0; j < 4; ++j)
                    dma16(g + 4 * (j * 256 + t), buf + 4 * (j * 256 + base));
            }
#pragma unroll
            for (int j = 0; j < 4; ++j) {
                uu[4 * j + 0] = flipu(__float_as_uint(v[j].x));
                uu[4 * j + 1] = flipu(__float_as_uint(v[j].y));
                uu[4 * j + 2] = flipu(__float_as_uint(v[j].z));
                uu[4 * j + 3] = flipu(__float_as_uint(v[j].w));
            }
        }
    }
}

extern "C" void kernel_launch(void* const* d_in, const int* in_sizes, int n_in,
                              void* d_out, int out_size, void* d_ws, size_t ws_size,
                              hipStream_t stream) {
    const float* X = (const float*)d_in[0];
    float* out = (float*)d_out;
    const int rows = in_sizes[0] / UNITS;
    const int kidx = (int)(0.7 * UNITS);  // 2867
    const int rpb = (rows % RPB == 0) ? RPB : 1;
    const int nblocks = rows / rpb;
    ksparse_select_kernel<<<nblocks, 256, 0, stream>>>(X, out, kidx, nblocks, rpb);
}

// Round 6
// 101.732 us; speedup vs baseline: 2.4895x; 1.2424x over previous
//
#include <hip/hip_runtime.h>
#include <stdint.h>

#define UNITS  4096
#define CAP    512        // LDS list capacity (window count ~355 +- 18; cap = +8.7 sigma)
#define NSLOT  (CAP / 64) // 8 per-lane slots for the wave-local select
#define LOF    0.40f      // theta window: theta ~= 0.5247 +- 0.0206; +-6 sigma bounds
#define HIF    0.65f
#define P0     0x3E000000u // common high-bit prefix of bits(0.40f)=0x3ECCCCCD, bits(0.65f)=0x3F266666
#define TOPBIT 24          // first differing bit of LOu/HIu

// LDS-only barrier: drain this wave's LDS ops then s_barrier (no vmcnt drain).
__device__ __forceinline__ void lds_barrier() {
    asm volatile("s_waitcnt lgkmcnt(0)" ::: "memory");
    __builtin_amdgcn_s_barrier();
}

// order-preserving float->uint map (fallback path only)
__device__ __forceinline__ uint32_t flipu(uint32_t b) {
    return b ^ (uint32_t)(((int32_t)b >> 31) | (int32_t)0x80000000);
}

// One block (256 threads) per row.
// Fast path: count-below-LO + compact window [LO,HI) into LDS list (1 barrier),
// then every wave redundantly radix-selects rank (k - cb) from the list via
// ballots (zero barriers), masks from registers. Exactness is checked per row;
// rows failing the bracket take the block-wide 32-bit bit-search fallback.
__global__ __launch_bounds__(256, 8) void ksparse_select_kernel(
        const float* __restrict__ X, float* __restrict__ out, int kidx) {
    __shared__ uint32_t list[CAP];  // 2 KiB
    __shared__ uint32_t cnt;
    __shared__ uint32_t wnb[4];     // per-wave count of elements < LO
    __shared__ uint32_t fbc[4];     // fallback per-wave counts

    const int t    = threadIdx.x;
    const int w    = t >> 6;
    const int lane = t & 63;
    const uint64_t lmlt = (1ull << lane) - 1ull;  // lanes below me

    if (t == 0) cnt = 0u;

    // load row (coalesced float4)
    float f[16];
    {
        const float4* Xv = reinterpret_cast<const float4*>(X + (size_t)blockIdx.x * UNITS);
        float4 a = Xv[t], b = Xv[256 + t], c2 = Xv[512 + t], d = Xv[768 + t];
        f[0] = a.x;  f[1] = a.y;  f[2] = a.z;  f[3] = a.w;
        f[4] = b.x;  f[5] = b.y;  f[6] = b.z;  f[7] = b.w;
        f[8] = c2.x; f[9] = c2.y; f[10] = c2.z; f[11] = c2.w;
        f[12] = d.x; f[13] = d.y; f[14] = d.z; f[15] = d.w;
    }

    lds_barrier();  // cnt zeroed everywhere

    // window ballots: count-below-LO (scalar popcounts) + window membership masks
    uint64_t mwin[16];
    uint32_t nbw = 0, wtot = 0;
#pragma unroll
    for (int e = 0; e < 16; ++e) {
        const bool lo = f[e] < LOF;
        const bool hi = f[e] < HIF;
        const uint64_t mlo = __ballot(lo);
        mwin[e] = __ballot(hi && !lo);
        nbw  += (uint32_t)__popcll(mlo);
        wtot += (uint32_t)__popcll(mwin[e]);
    }
    if (lane == 0) wnb[w] = nbw;

    // reserve list space: ONE atomic per wave, then ballot-ranked scatter
    uint32_t base = 0;
    if (lane == 0) base = atomicAdd(&cnt, wtot);
    base = __shfl(base, 0);
    uint32_t pfx = 0;
#pragma unroll
    for (int e = 0; e < 16; ++e) {
        if (mwin[e] & (1ull << lane)) {
            const uint32_t idx = base + pfx + (uint32_t)__popcll(mwin[e] & lmlt);
            if (idx < CAP) list[idx] = __float_as_uint(f[e]);  // positive floats: bits are order-preserving
        }
        pfx += (uint32_t)__popcll(mwin[e]);
    }

    lds_barrier();  // list + cnt + wnb visible

    const uint32_t c  = cnt;
    const uint32_t cb = wnb[0] + wnb[1] + wnb[2] + wnb[3];
    const uint32_t k  = (uint32_t)kidx;

    float4* Ov = reinterpret_cast<float4*>(out + (size_t)blockIdx.x * UNITS);

    if (cb <= k && k < cb + c && c <= CAP) {   // block-uniform bracket check
        const uint32_t r = k - cb;             // rank of theta within the list

        // every wave loads the whole list (64-lane distributed), sentinel-padded
        uint32_t sv[NSLOT];
#pragma unroll
        for (int i = 0; i < NSLOT; ++i) {
            const uint32_t ix = (uint32_t)lane + 64u * i;
            sv[i] = (ix < c) ? list[ix] : 0xFFFFFFFFu;
        }

        // MSB-first ballot radix select: p converges to the exact bits of theta
        uint32_t p = P0;
#pragma unroll 1
        for (int b = TOPBIT; b >= 0; --b) {
            const uint32_t mid = p | (1u << b);
            uint32_t cm = 0;
#pragma unroll
            for (int i = 0; i < NSLOT; ++i)
                cm += (uint32_t)__popcll(__ballot(sv[i] < mid));
            if (cm <= r) p = mid;   // wave-uniform
        }
        const float th = __uint_as_float(p);

#pragma unroll
        for (int j = 0; j < 4; ++j) {
            float4 o;
            o.x = (f[4 * j + 0] >= th) ? f[4 * j + 0] : 0.0f;
            o.y = (f[4 * j + 1] >= th) ? f[4 * j + 1] : 0.0f;
            o.z = (f[4 * j + 2] >= th) ? f[4 * j + 2] : 0.0f;
            o.w = (f[4 * j + 3] >= th) ? f[4 * j + 3] : 0.0f;
            Ov[j * 256 + t] = o;
        }
    } else {
        // exact block-wide fallback: 32-bit MSB bit-search in flipped space
        uint32_t uu[16];
#pragma unroll
        for (int e = 0; e < 16; ++e) uu[e] = flipu(__float_as_uint(f[e]));
        uint32_t p = 0;
#pragma unroll 1
        for (int b = 31; b >= 0; --b) {
            const uint32_t mid = p | (1u << b);
            uint32_t cw = 0;
#pragma unroll
            for (int e = 0; e < 16; ++e)
                cw += (uint32_t)__popcll(__ballot(uu[e] < mid));
            if (lane == 0) fbc[w] = cw;
            lds_barrier();
            const uint32_t cm = fbc[0] + fbc[1] + fbc[2] + fbc[3];
            if (cm <= k) p = mid;   // block-uniform
            lds_barrier();          // fbc consumed before next overwrite
        }
#pragma unroll
        for (int j = 0; j < 4; ++j) {
            float4 o;
            o.x = (uu[4 * j + 0] >= p) ? f[4 * j + 0] : 0.0f;
            o.y = (uu[4 * j + 1] >= p) ? f[4 * j + 1] : 0.0f;
            o.z = (uu[4 * j + 2] >= p) ? f[4 * j + 2] : 0.0f;
            o.w = (uu[4 * j + 3] >= p) ? f[4 * j + 3] : 0.0f;
            Ov[j * 256 + t] = o;
        }
    }
}

extern "C" void kernel_launch(void* const* d_in, const int* in_sizes, int n_in,
                              void* d_out, int out_size, void* d_ws, size_t ws_size,
                              hipStream_t stream) {
    const float* X = (const float*)d_in[0];
    float* out = (float*)d_out;
    const int rows = in_sizes[0] / UNITS;
    const int kidx = (int)(0.7 * UNITS);  // 2867
    ksparse_select_kernel<<<rows, 256, 0, stream>>>(X, out, kidx);
}